// Round 8
// baseline (41.674 us; speedup 1.0000x reference)
//
#include <hip/hip_runtime.h>
#include <hip/hip_bf16.h>

typedef __attribute__((ext_vector_type(8))) short bf16x8;
typedef __attribute__((ext_vector_type(4))) float f32x4;

#define NPIX 32768

// ws byte layout:
//   [0, 32768)      W1fT bf16 [64 d][256 c]   (BN scale folded)
//   [32768, 51200)  W2T  bf16 [144 e][64 d]
//   [51200, 51456)  b1f  f32  [64]            (BN-folded bias)

__device__ __forceinline__ ushort f2bf(float f) {
    __hip_bfloat16 h = __float2bfloat16(f);   // single v_cvt, RNE
    ushort u; __builtin_memcpy(&u, &h, 2);
    return u;
}

__global__ __launch_bounds__(256) void fold_kernel(
        const float* __restrict__ W1, const float* __restrict__ b1,
        const float* __restrict__ gamma, const float* __restrict__ beta,
        const float* __restrict__ mean, const float* __restrict__ var,
        const float* __restrict__ W2, void* __restrict__ ws) {
    ushort* w1t = (ushort*)ws;
    ushort* w2t = (ushort*)ws + 16384;
    float*  b1f = (float*)((char*)ws + 51200);
    int tid = blockIdx.x * 256 + threadIdx.x;
    if (tid < 16384) {
        int d = tid >> 8, c = tid & 255;
        float scale = gamma[d] * rsqrtf(var[d] + 1e-3f);
        w1t[tid] = f2bf(W1[c * 64 + d] * scale);       // W1fT[d][c]
    }
    if (tid < 9216) {
        int e = tid >> 6, d = tid & 63;
        w2t[tid] = f2bf(W2[d * 144 + e]);              // W2T[e][d]
    }
    if (tid < 64) {
        float scale = gamma[tid] * rsqrtf(var[tid] + 1e-3f);
        b1f[tid] = (b1[tid] - mean[tid]) * scale + beta[tid];
    }
}

// Fully fused, ZERO barriers: every phase is wave-private.
// Block = 1 image row (64 px), 256 threads (4 waves); wave owns 16 px
// end-to-end. Weights read from global (L2-hot). ker is written with
// regular stores and re-read through L1/L2 in the involution phase
// (64 B/tap broadcast) -- no LDS broadcast buffer needed.
// LDS 40 KB: xs [64][512B] swizzled bf16 x | hs [64][128B] swizzled bf16 h.
// XCD swizzle: XCD k owns image k (4 MB ~= its L2) for halo-row locality.
__global__ __launch_bounds__(256, 3) void fused_kernel(
        const float* __restrict__ x, const void* __restrict__ ws,
        const float* __restrict__ b2, float* ker,   // NOT restrict: read back
        float* __restrict__ out) {
    __shared__ __align__(16) char smem[40960];
    ushort* xs = (ushort*)smem;              // [64 rows][512 B]
    ushort* hs = (ushort*)(smem + 32768);    // [64 rows][128 B]
    const int t = threadIdx.x;
    const int wv = t >> 6, ln = t & 63;
    const int bid = (int)blockIdx.x;
    const int lb = (bid & 7) * 64 + (bid >> 3);  // XCD k <- image k
    const int p0 = lb * 64;
    const ushort* w1t = (const ushort*)ws;
    const ushort* w2t = (const ushort*)ws + 16384;
    const float*  b1f = (const float*)((const char*)ws + 51200);
    const int r16 = ln & 15, g = ln >> 4;

    // ---- stage wave's own 16 x-rows: f32 -> bf16, XOR-swizzled ----
    {
        const float4* xg = (const float4*)(x + (size_t)(p0 + wv * 16) * 256);
        #pragma unroll
        for (int it = 0; it < 16; it++) {
            int p = wv * 16 + it;
            float4 v = xg[it * 64 + ln];
            ushort4 b4; b4.x = f2bf(v.x); b4.y = f2bf(v.y);
            b4.z = f2bf(v.z); b4.w = f2bf(v.w);
            int bcol = (ln * 8) ^ ((p & 7) << 4);
            *(ushort4*)((char*)xs + p * 512 + bcol) = b4;
        }
    }

    // ---- GEMM1: 16 px x 64 d per wave; W1 fragments from global ----
    const int prow = wv * 16 + r16;
    f32x4 acc[4];
    #pragma unroll
    for (int dt = 0; dt < 4; dt++) {
        float bv = b1f[dt * 16 + r16];
        acc[dt] = (f32x4){bv, bv, bv, bv};
    }
    #pragma unroll
    for (int kk = 0; kk < 8; kk++) {
        int bcA = (kk * 64 + g * 16) ^ ((r16 & 7) << 4);
        bf16x8 av = *(const bf16x8*)((const char*)xs + prow * 512 + bcA);
        #pragma unroll
        for (int dt = 0; dt < 4; dt++) {
            bf16x8 bv = *(const bf16x8*)(w1t + (dt * 16 + r16) * 256 + kk * 32 + g * 8);
            acc[dt] = __builtin_amdgcn_mfma_f32_16x16x32_bf16(av, bv, acc[dt], 0, 0, 0);
        }
    }

    // relu -> bf16 -> hs (wave-private rows, swizzled)
    #pragma unroll
    for (int dt = 0; dt < 4; dt++) {
        #pragma unroll
        for (int r = 0; r < 4; r++) {
            int pxl = wv * 16 + g * 4 + r;            // C/D: row=(l>>4)*4+reg, col=l&15
            int bcol = ((dt * 16 + r16) * 2) ^ ((pxl & 7) << 4);
            *(ushort*)((char*)hs + pxl * 128 + bcol) = f2bf(fmaxf(acc[dt][r], 0.f));
        }
    }

    // ---- GEMM2: 16 px x 144 e per wave; W2 fragments from global ----
    f32x4 acc2[9];
    #pragma unroll
    for (int et = 0; et < 9; et++) {
        float bv = b2[et * 16 + r16];
        acc2[et] = (f32x4){bv, bv, bv, bv};
    }
    #pragma unroll
    for (int kk = 0; kk < 2; kk++) {
        int bcA = (kk * 64 + g * 16) ^ ((r16 & 7) << 4);
        bf16x8 av = *(const bf16x8*)((const char*)hs + prow * 128 + bcA);
        #pragma unroll
        for (int et = 0; et < 9; et++) {
            bf16x8 bv = *(const bf16x8*)(w2t + (et * 16 + r16) * 64 + kk * 32 + g * 8);
            acc2[et] = __builtin_amdgcn_mfma_f32_16x16x32_bf16(av, bv, acc2[et], 0, 0, 0);
        }
    }

    // ---- ker: regular stores (L2-resident; harness output) ----
    #pragma unroll
    for (int et = 0; et < 9; et++) {
        #pragma unroll
        for (int r = 0; r < 4; r++) {
            int pxl = wv * 16 + g * 4 + r;
            ker[(size_t)(p0 + pxl) * 144 + et * 16 + r16] = acc2[et][r];
        }
    }

    // ---- involution: shift-register 3x3 window; ker re-read via L1/L2 ----
    const int i  = lb & 63;
    const int s4 = (ln & 3) * 4;
    const f32x4* xv4 = (const f32x4*)x;
    const int j0 = wv * 16;
    const f32x4 z4 = {0.f, 0.f, 0.f, 0.f};

    f32x4 wmL[3], wmC[3], wmN[3];
    #pragma unroll
    for (int r = 0; r < 3; r++) {
        int row = i + r - 1;
        bool rv = (unsigned)row < 64u;
        wmL[r] = (rv && j0 > 0)
            ? xv4[(size_t)((lb + r - 1) * 64 + (j0 - 1)) * 64 + ln] : z4;
        wmC[r] = rv
            ? xv4[(size_t)((lb + r - 1) * 64 + j0) * 64 + ln] : z4;
    }
    #pragma unroll 4
    for (int pp = 0; pp < 16; pp++) {
        const int j = j0 + pp;
        const bool cv = (j + 1) < 64;
        #pragma unroll
        for (int r = 0; r < 3; r++) {
            int row = i + r - 1;
            bool rv = (unsigned)row < 64u;
            wmN[r] = (rv && cv)
                ? xv4[(size_t)((lb + r - 1) * 64 + (j + 1)) * 64 + ln] : z4;
        }
        const float* kp = ker + (size_t)(p0 + j) * 144 + s4;
        f32x4 o = {0.f, 0.f, 0.f, 0.f};
        #pragma unroll
        for (int r = 0; r < 3; r++) {
            o += (*(const f32x4*)(kp + (r * 3 + 0) * 16)) * wmL[r];
            o += (*(const f32x4*)(kp + (r * 3 + 1) * 16)) * wmC[r];
            o += (*(const f32x4*)(kp + (r * 3 + 2) * 16)) * wmN[r];
        }
        __builtin_nontemporal_store(o, &((f32x4*)out)[(size_t)(p0 + j) * 64 + ln]);
        #pragma unroll
        for (int r = 0; r < 3; r++) { wmL[r] = wmC[r]; wmC[r] = wmN[r]; }
    }
}

extern "C" void kernel_launch(void* const* d_in, const int* in_sizes, int n_in,
                              void* d_out, int out_size, void* d_ws, size_t ws_size,
                              hipStream_t stream) {
    const float* x     = (const float*)d_in[0];
    const float* W1    = (const float*)d_in[1];
    const float* b1    = (const float*)d_in[2];
    const float* gamma = (const float*)d_in[3];
    const float* beta  = (const float*)d_in[4];
    const float* mmean = (const float*)d_in[5];
    const float* mvar  = (const float*)d_in[6];
    const float* W2    = (const float*)d_in[7];
    const float* b2    = (const float*)d_in[8];

    float* out_main = (float*)d_out;                 // (B,H,W,C)   = 8388608 f32
    float* out_ker  = (float*)d_out + 8388608;       // (B,H,W,144) = 4718592 f32

    fold_kernel<<<64, 256, 0, stream>>>(W1, b1, gamma, beta, mmean, mvar, W2, d_ws);
    fused_kernel<<<NPIX / 64, 256, 0, stream>>>(x, d_ws, b2, out_ker, out_main);
}

// Round 9
// 36.206 us; speedup vs baseline: 1.1510x; 1.1510x over previous
//
#include <hip/hip_runtime.h>
#include <hip/hip_bf16.h>

typedef __attribute__((ext_vector_type(8))) short bf16x8;
typedef __attribute__((ext_vector_type(4))) float f32x4;

#define NPIX 32768

// ws byte layout:
//   [0, 32768)      W1fT bf16 [64 d][256 c]   (BN scale folded)
//   [32768, 51200)  W2T  bf16 [144 e][64 d]
//   [51200, 51456)  b1f  f32  [64]            (BN-folded bias)

__device__ __forceinline__ ushort f2bf(float f) {
    __hip_bfloat16 h = __float2bfloat16(f);   // single v_cvt, RNE
    ushort u; __builtin_memcpy(&u, &h, 2);
    return u;
}

__global__ __launch_bounds__(256) void fold_kernel(
        const float* __restrict__ W1, const float* __restrict__ b1,
        const float* __restrict__ gamma, const float* __restrict__ beta,
        const float* __restrict__ mean, const float* __restrict__ var,
        const float* __restrict__ W2, void* __restrict__ ws) {
    ushort* w1t = (ushort*)ws;
    ushort* w2t = (ushort*)ws + 16384;
    float*  b1f = (float*)((char*)ws + 51200);
    int tid = blockIdx.x * 256 + threadIdx.x;
    if (tid < 16384) {
        int d = tid >> 8, c = tid & 255;
        float scale = gamma[d] * rsqrtf(var[d] + 1e-3f);
        w1t[tid] = f2bf(W1[c * 64 + d] * scale);       // W1fT[d][c]
    }
    if (tid < 9216) {
        int e = tid >> 6, d = tid & 63;
        w2t[tid] = f2bf(W2[d * 144 + e]);              // W2T[e][d]
    }
    if (tid < 64) {
        float scale = gamma[tid] * rsqrtf(var[tid] + 1e-3f);
        b1f[tid] = (b1[tid] - mean[tid]) * scale + beta[tid];
    }
}

// Fully fused, ZERO barriers, wave-private LDS arenas (10240 B per wave):
//   phase A: xs bf16 [16 rows][512 B] @arena+0, swizzled   (x tile)
//   phase B: hs bf16 [16 rows][128 B] @arena+8192, swizzled (relu(h))
//   phase C: ks f32  [16 rows][148]   @arena+0 (9472 B; aliases xs+hs --
//            safe: written after GEMM2, within-wave program order, and no
//            cross-wave sharing)
// Total LDS 40960 B -> 4 blocks/CU -> 16 waves/CU.
// Block = 1 image row (64 px), 4 waves, wave owns 16 px end-to-end.
// Weights from global (L2-hot). Involution: ks from LDS, shift-register
// 3x3 x-window (3 taps/px), NT stores for out; ker NT-stored once.
__global__ __launch_bounds__(256, 4) void fused_kernel(
        const float* __restrict__ x, const void* __restrict__ ws,
        const float* __restrict__ b2, float* __restrict__ ker,
        float* __restrict__ out) {
    __shared__ __align__(16) char smem[40960];
    const int t = threadIdx.x;
    const int wv = t >> 6, ln = t & 63;
    char* arena = smem + wv * 10240;
    const int bid = (int)blockIdx.x;
    const int lb = (bid & 7) * 64 + (bid >> 3);  // XCD k <- image k
    const int p0 = lb * 64;
    const ushort* w1t = (const ushort*)ws;
    const ushort* w2t = (const ushort*)ws + 16384;
    const float*  b1f = (const float*)((const char*)ws + 51200);
    const int r16 = ln & 15, g = ln >> 4;

    // ---- stage wave's 16 x-rows: f32 -> bf16, XOR-swizzled, local rows ----
    {
        const float4* xg = (const float4*)(x + (size_t)(p0 + wv * 16) * 256);
        #pragma unroll
        for (int it = 0; it < 16; it++) {
            float4 v = xg[it * 64 + ln];
            ushort4 b4; b4.x = f2bf(v.x); b4.y = f2bf(v.y);
            b4.z = f2bf(v.z); b4.w = f2bf(v.w);
            int bcol = (ln * 8) ^ ((it & 7) << 4);
            *(ushort4*)(arena + it * 512 + bcol) = b4;
        }
    }

    // ---- GEMM1: 16 px x 64 d; A from arena xs, B from global W1fT ----
    f32x4 acc[4];
    #pragma unroll
    for (int dt = 0; dt < 4; dt++) {
        float bv = b1f[dt * 16 + r16];
        acc[dt] = (f32x4){bv, bv, bv, bv};
    }
    #pragma unroll
    for (int kk = 0; kk < 8; kk++) {
        int bcA = (kk * 64 + g * 16) ^ ((r16 & 7) << 4);
        bf16x8 av = *(const bf16x8*)(arena + r16 * 512 + bcA);
        #pragma unroll
        for (int dt = 0; dt < 4; dt++) {
            bf16x8 bv = *(const bf16x8*)(w1t + (dt * 16 + r16) * 256 + kk * 32 + g * 8);
            acc[dt] = __builtin_amdgcn_mfma_f32_16x16x32_bf16(av, bv, acc[dt], 0, 0, 0);
        }
    }

    // relu -> bf16 -> hs (arena+8192, local rows 0..15, swizzled)
    #pragma unroll
    for (int dt = 0; dt < 4; dt++) {
        #pragma unroll
        for (int r = 0; r < 4; r++) {
            int q = g * 4 + r;                        // local px (C/D row)
            int bcol = ((dt * 16 + r16) * 2) ^ ((q & 7) << 4);
            *(ushort*)(arena + 8192 + q * 128 + bcol) = f2bf(fmaxf(acc[dt][r], 0.f));
        }
    }

    // ---- GEMM2: 16 px x 144 e; A from hs, B from global W2T ----
    f32x4 acc2[9];
    #pragma unroll
    for (int et = 0; et < 9; et++) {
        float bv = b2[et * 16 + r16];
        acc2[et] = (f32x4){bv, bv, bv, bv};
    }
    #pragma unroll
    for (int kk = 0; kk < 2; kk++) {
        int bcA = (kk * 64 + g * 16) ^ ((r16 & 7) << 4);
        bf16x8 av = *(const bf16x8*)(arena + 8192 + r16 * 128 + bcA);
        #pragma unroll
        for (int et = 0; et < 9; et++) {
            bf16x8 bv = *(const bf16x8*)(w2t + (et * 16 + r16) * 64 + kk * 32 + g * 8);
            acc2[et] = __builtin_amdgcn_mfma_f32_16x16x32_bf16(av, bv, acc2[et], 0, 0, 0);
        }
    }

    // ---- ker: NT store to global + f32 ks in wave arena (aliases xs/hs) ----
    float* ksf = (float*)arena;                       // [16][148]
    #pragma unroll
    for (int et = 0; et < 9; et++) {
        #pragma unroll
        for (int r = 0; r < 4; r++) {
            int q = g * 4 + r;
            int e = et * 16 + r16;
            float v = acc2[et][r];
            __builtin_nontemporal_store(v, &ker[(size_t)(p0 + wv * 16 + q) * 144 + e]);
            ksf[q * 148 + e] = v;
        }
    }

    // ---- involution: shift-register 3x3 window; ks from LDS ----
    const int i  = lb & 63;
    const int s4 = (ln & 3) * 4;
    const f32x4* xv4 = (const f32x4*)x;
    const int j0 = wv * 16;
    const f32x4 z4 = {0.f, 0.f, 0.f, 0.f};

    f32x4 wmL[3], wmC[3], wmN[3];
    #pragma unroll
    for (int r = 0; r < 3; r++) {
        int row = i + r - 1;
        bool rv = (unsigned)row < 64u;
        wmL[r] = (rv && j0 > 0)
            ? xv4[(size_t)((lb + r - 1) * 64 + (j0 - 1)) * 64 + ln] : z4;
        wmC[r] = rv
            ? xv4[(size_t)((lb + r - 1) * 64 + j0) * 64 + ln] : z4;
    }
    #pragma unroll 4
    for (int pp = 0; pp < 16; pp++) {
        const int j = j0 + pp;
        const bool cv = (j + 1) < 64;
        #pragma unroll
        for (int r = 0; r < 3; r++) {
            int row = i + r - 1;
            bool rv = (unsigned)row < 64u;
            wmN[r] = (rv && cv)
                ? xv4[(size_t)((lb + r - 1) * 64 + (j + 1)) * 64 + ln] : z4;
        }
        const float* kp = ksf + pp * 148 + s4;
        f32x4 o = {0.f, 0.f, 0.f, 0.f};
        #pragma unroll
        for (int r = 0; r < 3; r++) {
            o += (*(const f32x4*)(kp + (r * 3 + 0) * 16)) * wmL[r];
            o += (*(const f32x4*)(kp + (r * 3 + 1) * 16)) * wmC[r];
            o += (*(const f32x4*)(kp + (r * 3 + 2) * 16)) * wmN[r];
        }
        __builtin_nontemporal_store(o, &((f32x4*)out)[(size_t)(p0 + j) * 64 + ln]);
        #pragma unroll
        for (int r = 0; r < 3; r++) { wmL[r] = wmC[r]; wmC[r] = wmN[r]; }
    }
}

extern "C" void kernel_launch(void* const* d_in, const int* in_sizes, int n_in,
                              void* d_out, int out_size, void* d_ws, size_t ws_size,
                              hipStream_t stream) {
    const float* x     = (const float*)d_in[0];
    const float* W1    = (const float*)d_in[1];
    const float* b1    = (const float*)d_in[2];
    const float* gamma = (const float*)d_in[3];
    const float* beta  = (const float*)d_in[4];
    const float* mmean = (const float*)d_in[5];
    const float* mvar  = (const float*)d_in[6];
    const float* W2    = (const float*)d_in[7];
    const float* b2    = (const float*)d_in[8];

    float* out_main = (float*)d_out;                 // (B,H,W,C)   = 8388608 f32
    float* out_ker  = (float*)d_out + 8388608;       // (B,H,W,144) = 4718592 f32

    fold_kernel<<<64, 256, 0, stream>>>(W1, b1, gamma, beta, mmean, mvar, W2, d_ws);
    fused_kernel<<<NPIX / 64, 256, 0, stream>>>(x, d_ws, b2, out_ker, out_main);
}